// Round 16
// baseline (30.633 us; speedup 1.0000x reference)
//
#include <hip/hip_runtime.h>
#include <stdint.h>

constexpr int Dz = 96, Hy = 160, Wx = 160;
constexpr int NVOX = Dz * Hy * Wx;

// Wave-autonomous tile: 32d x 8w x 1h per WAVE; 2 waves per 128-thread block.
// Stage-1 footprint per wave: 6 z-rows x 2 y-rows x 56-dword aligned x-pitch.
constexpr int ZW = 6, YW = 2, XP = 56;          // LDS plane: [6][2][56] dwords
constexpr int ROWS = ZW * YW;                   // 12 (z,y) rows
constexpr int NCHUNK = ROWS * 14;               // 168 16B chunks per plane
constexpr int UI = 3;                           // chunk batches (3*64 >= 168)
constexpr int WBUF = UI * 64 * 4;               // 768 dwords per wave buffer

#define WAIT_LGKM() do { asm volatile("s_waitcnt lgkmcnt(0)" ::: "memory"); \
                         __builtin_amdgcn_sched_barrier(0); } while (0)
#define FENCE() __builtin_amdgcn_sched_barrier(0)

__global__ __launch_bounds__(128) void st_fused_kernel(
    const float* __restrict__ src,
    const float* __restrict__ flows,
    const float* __restrict__ rfp,
    float* __restrict__ out)
{
    __shared__ float raw[2][WBUF];      // 6 KB: one summed-plane buffer per wave
    const int t = threadIdx.x;
    const int lane = t & 63;

    // XCD-aware bijective swizzle (4800 = 8 x 600), then wave-linear tiling.
    // Tile coords are wave-uniform: force to SGPR via readfirstlane.
    const int bid = blockIdx.x;
    const int swz = (bid & 7) * 600 + (bid >> 3);
    const int wid = __builtin_amdgcn_readfirstlane(swz * 2 + (t >> 6));  // 0..9599
    const int wt = wid % 20;            // w-tile (8 w each)
    const int rest = wid / 20;
    const int dt = rest % 3;            // d-tile (32 d each)
    const int h0 = rest / 3;            // h row 0..159
    const int w0w = wt * 8, d0 = dt * 32;
    const int v = t >> 6;               // wave id 0..1 (LDS bank select)
    const float rf = *rfp;

    const int Z0w = (19 * w0w) >> 5;
    const int X0 = 53 * dt;             // (53*d0)/32 exact
    const int X0a = X0 & ~3;            // 16B-aligned x origin
    const int YB = (159 * h0) / 160;    // single h -> y0i == YB always

    // ---- 3 live chunk addresses (16B each), advanced by channel stride ----
    const char* ap[UI];
    {
        const char* fb = (const char*)flows + ((size_t)YB * Wx + X0a) * 4;
#pragma unroll
        for (int u = 0; u < UI; ++u) {
            int c = u * 64 + lane;
            if (c >= NCHUNK) c = NCHUNK - 1;     // tail dups (LDS junk, never read)
            int row = c / 14, ch = c - row * 14;
            int zr = row >> 1, yr = row & 1;
            ap[u] = fb + ((size_t)(zr * Hy + yr) * Wx + (size_t)Z0w * Hy * Wx) * 4 + ch * 16;
        }
    }

    // ---- channel staging: two alternating 3-chunk batch sets (24 VGPR peak).
    // Linearity: sum the 3 flow stages BEFORE interpolating (same sample coords).
    float* const lb = &raw[v][0];
    float4 bA[3], bB[3];
#define LOADB(SET, U) do { \
    _Pragma("unroll") \
    for (int i = 0; i < 3; ++i) \
        SET[i] = *(const float4*)(ap[U] + (size_t)i * (3u * NVOX * 4u)); \
    ap[U] += (size_t)NVOX * 4; } while (0)
#define STOREB(SET, U) do { \
    float4 s; \
    s.x = (SET[0].x + SET[1].x) + SET[2].x; \
    s.y = (SET[0].y + SET[1].y) + SET[2].y; \
    s.z = (SET[0].z + SET[1].z) + SET[2].z; \
    s.w = (SET[0].w + SET[1].w) + SET[2].w; \
    ((float4*)lb)[(U) * 64 + lane] = s; } while (0)

    // ---- compute mapping: lanes vary d (stage-2 x axis = stride 1) ----
    const int dl = lane & 31;
    const int half = lane >> 5;         // picks w quartet
    const int d = d0 + dl;

    const float xf = (float)(53 * d) * (1.0f / 32.0f);
    const int   x0i = (int)xf;
    const float fx  = xf - (float)x0i;
    const int   xx  = x0i - X0a;        // 0..54
    const float wxa = 1.0f - fx, wxb = fx;

    // z-row factorization: all 4 k's (zz,zz+1) pairs live in 4 consecutive rows.
    int rowoff[4];
    float wkz[4][4];
    {
        int zzk[4]; float wz0k[4], wz1k[4];
#pragma unroll
        for (int k = 0; k < 4; ++k) {
            const int w = w0w + 4 * half + k;
            const float zf = (float)(19 * w) * (1.0f / 32.0f);
            const int z0i = (int)zf;
            const float fz = zf - (float)z0i;
            zzk[k] = z0i - Z0w;         // 0..4, nondecreasing in k
            wz0k[k] = 1.0f - fz; wz1k[k] = fz;
        }
        const int zz0 = zzk[0];
#pragma unroll
        for (int r = 0; r < 4; ++r) {
            rowoff[r] = min(zz0 + r, ZW - 1) * (YW * XP);
#pragma unroll
            for (int k = 0; k < 4; ++k) {
                const int rel = zzk[k] - zz0;            // 0..2
                wkz[r][k] = (rel == r) ? wz0k[k] : ((rel == r - 1) ? wz1k[k] : 0.0f);
            }
        }
    }

    // y-interp: single h, yrel == 0 -> 2 terms
    const float fy = (float)h0 * (159.0f / 160.0f) - (float)YB;
    const float wy0 = 1.0f - fy, wy1 = fy;

    // 8 row-pair LDS reads per channel; sparse wkz scatters rows into 4 k outputs.
    auto compute = [&](float (&acc)[4]) {
#pragma unroll
        for (int yy = 0; yy < 2; ++yy) {
            float zv0 = 0.f, zv1 = 0.f, zv2 = 0.f, zv3 = 0.f;
#pragma unroll
            for (int r = 0; r < 4; ++r) {
                const float* p = lb + rowoff[r] + yy * XP + xx;
                const float xv = wxa * p[0] + wxb * p[1];
                zv0 += wkz[r][0] * xv;
                zv1 += wkz[r][1] * xv;
                zv2 += wkz[r][2] * xv;
                zv3 += wkz[r][3] * xv;
            }
            const float wy = yy ? wy1 : wy0;
            acc[0] += wy * zv0;
            acc[1] += wy * zv1;
            acc[2] += wy * zv2;
            acc[3] += wy * zv3;
        }
    };

    float accA[4] = {0.f, 0.f, 0.f, 0.f};
    float accB[4] = {0.f, 0.f, 0.f, 0.f};
    float accC[4] = {0.f, 0.f, 0.f, 0.f};

    // ---- 3-phase pipeline; next channel's loads in flight under compute ----
    LOADB(bA, 0); LOADB(bB, 1);         // ch0
    STOREB(bA, 0); LOADB(bA, 2);
    STOREB(bB, 1); STOREB(bA, 2);
    LOADB(bA, 0); LOADB(bB, 1);         // ch1 first batches
    compute(accA);                      // ch0
    FENCE();
    STOREB(bA, 0); LOADB(bA, 2);
    STOREB(bB, 1); STOREB(bA, 2);
    LOADB(bA, 0); LOADB(bB, 1);         // ch2 first batches
    compute(accB);                      // ch1
    FENCE();
    STOREB(bA, 0); LOADB(bA, 2);
    STOREB(bB, 1); STOREB(bA, 2);
    compute(accC);                      // ch2
#undef LOADB
#undef STOREB

    // ---- stage 2: row-paired src sampling (zeros mode); results straight to
    // wave-private transpose LDS (same-wave ordering) ----
    float* tr = &raw[v][0];             // [32][9] dwords (288 <= 768)
#pragma unroll
    for (int k = 0; k < 4; ++k) {
        const int w = w0w + 4 * half + k;
        const float f0 = (float)d + accA[k] * rf;    // -> x axis of src
        const float f1 = (float)h0 + accB[k] * rf;   // -> y axis
        const float f2 = (float)w + accC[k] * rf;    // -> z axis

        const float xs = f0 * (159.0f / 95.0f);
        const float ys = f1;
        const float zs = f2 * (95.0f / 159.0f);

        const float xf0 = floorf(xs), yf0 = floorf(ys), zf0 = floorf(zs);
        const float gx = xs - xf0, gy = ys - yf0, gz = zs - zf0;
        const int xi0 = (int)xf0, yi0 = (int)yf0, zi0 = (int)zf0;

        const int xc = min(max(xi0, 0), Wx - 2);
        const bool sx0 = (xi0 == xc);
        const float wx0m = ((unsigned)xi0 < (unsigned)Wx) ? (1.0f - gx) : 0.0f;
        const float wx1m = ((unsigned)(xi0 + 1) < (unsigned)Wx) ? gx : 0.0f;

        const int yc0 = min(max(yi0, 0), Hy - 1);
        const int yc1 = min(max(yi0 + 1, 0), Hy - 1);
        const int zc0 = min(max(zi0, 0), Dz - 1);
        const int zc1 = min(max(zi0 + 1, 0), Dz - 1);
        const float wy0m = ((unsigned)yi0 < (unsigned)Hy) ? (1.0f - gy) : 0.0f;
        const float wy1m = ((unsigned)(yi0 + 1) < (unsigned)Hy) ? gy : 0.0f;
        const float wz0m = ((unsigned)zi0 < (unsigned)Dz) ? (1.0f - gz) : 0.0f;
        const float wz1m = ((unsigned)(zi0 + 1) < (unsigned)Dz) ? gz : 0.0f;

        const float w00 = wz0m * wy0m, w01 = wz0m * wy1m;
        const float w10 = wz1m * wy0m, w11 = wz1m * wy1m;

        float r = 0.0f;
        auto rowadd = [&](int zc, int yc, float wt) {
            const float* p = src + ((size_t)zc * Hy + yc) * Wx + xc;
            const float va = p[0], vb = p[1];
            const float s0 = sx0 ? va : vb;   // value at xi0 (xi0==159 -> vb)
            const float s1 = sx0 ? vb : va;   // value at xi1 (xi0==-1 -> va)
            r += wt * (wx0m * s0 + wx1m * s1);
        };
        rowadd(zc0, yc0, w00);
        rowadd(zc0, yc1, w01);
        rowadd(zc1, yc0, w10);
        rowadd(zc1, yc1, w11);

        tr[dl * 9 + 4 * half + k] = r;
    }
    WAIT_LGKM();

    const int rrow = lane >> 3;         // 0..7
    const int rcol = lane & 7;          // 0..7
#pragma unroll
    for (int m = 0; m < 4; ++m) {
        const int dr = m * 8 + rrow;
        out[((size_t)(d0 + dr) * Hy + h0) * Wx + (w0w + rcol)] =
            tr[dr * 9 + rcol];
    }
}

extern "C" void kernel_launch(void* const* d_in, const int* in_sizes, int n_in,
                              void* d_out, int out_size, void* d_ws, size_t ws_size,
                              hipStream_t stream) {
    const float* src   = (const float*)d_in[0];
    const float* flows = (const float*)d_in[1];
    const float* rfp   = (const float*)d_in[2];
    float* out = (float*)d_out;

    st_fused_kernel<<<dim3(4800), 128, 0, stream>>>(src, flows, rfp, out);
}